// Round 1
// 528.497 us; speedup vs baseline: 1.2477x; 1.2477x over previous
//
#include <hip/hip_runtime.h>
#include <math.h>

#define B 32
#define C 512
#define HIDDEN 64
#define HW 4096          // 64*64
#define NBASES 8         // GRID_SIZE + SPLINE_ORDER
#define NKNOTS 12        // GRID_SIZE + 2*SPLINE_ORDER + 1

__device__ __forceinline__ float wave_reduce(float v) {
    #pragma unroll
    for (int m = 32; m > 0; m >>= 1) v += __shfl_xor(v, m, 64);
    return v;
}

__device__ __forceinline__ float silu_f(float x) {
    return x / (1.0f + __expf(-x));
}

// Cox-de Boor recursion, order 3, 12 knots -> 8 bases. Matches reference
// b_splines() exactly (indicator init, forward in-place update).
__device__ __forceinline__ void compute_bases(float x, const float* g, float* out) {
    float b[11];
    #pragma unroll
    for (int j = 0; j < 11; ++j)
        b[j] = (x >= g[j] && x < g[j + 1]) ? 1.0f : 0.0f;
    #pragma unroll
    for (int k = 1; k <= 3; ++k) {
        #pragma unroll
        for (int j = 0; j + k < 11; ++j) {
            float left  = (x - g[j]) / (g[j + k] - g[j]) * b[j];
            float right = (g[j + k + 1] - x) / (g[j + k + 1] - g[j + 1]) * b[j + 1];
            b[j] = left + right;
        }
    }
    #pragma unroll
    for (int j = 0; j < NBASES; ++j) out[j] = b[j];
}

// Kernel 1: per-(b,c) spatial mean. One WAVE per plane (no barrier), 4 planes/block.
__global__ __launch_bounds__(256) void mean_kernel(const float* __restrict__ x,
                                                   float* __restrict__ s) {
    const int wave = threadIdx.x >> 6, lane = threadIdx.x & 63;
    const int plane = blockIdx.x * 4 + wave;
    const float4* xp = (const float4*)(x + (size_t)plane * HW);
    float acc = 0.0f;
    #pragma unroll
    for (int j = 0; j < 16; ++j) {
        float4 v = xp[lane + j * 64];
        acc += (v.x + v.y) + (v.z + v.w);
    }
    acc = wave_reduce(acc);
    if (lane == 0) {
        float m = acc * (1.0f / (float)HW);
        if (isnan(m)) m = 0.0f;                       // nan_to_num
        if (isinf(m)) m = (m > 0.f) ? 3.4028235e38f : -3.4028235e38f;
        s[plane] = m;
    }
}

// Kernel 2: KAN layer 1 + inter-layer silu. One block per (b, 4 outputs).
// grid = B * (HIDDEN/4) = 512 blocks. Phase A (feature staging) identical to
// the proven version; Phase B: 4 waves, one output each.
__global__ __launch_bounds__(256) void kan1_kernel(
        const float* __restrict__ s,        // [B, C]
        const float* __restrict__ grid1,    // [C, 12] (rows identical)
        const float* __restrict__ bw1,      // [HIDDEN, C]
        const float* __restrict__ sw1,      // [HIDDEN, C, 8]
        const float* __restrict__ sc1,      // [HIDDEN, C]
        float* __restrict__ s1x2)           // [B, HIDDEN] = silu(layer-1 out)
{
    const int b     = blockIdx.x >> 4;          // 16 blocks per batch row
    const int obase = (blockIdx.x & 15) << 2;   // 4 outputs per block
    const int tid = threadIdx.x;
    const int wave = tid >> 6, lane = tid & 63;

    __shared__ float feat[C * 9];   // per feature: [silu, bases0..7] (18 KiB)

    float g1[NKNOTS];
    #pragma unroll
    for (int j = 0; j < NKNOTS; ++j) g1[j] = grid1[j];

    // Phase A: layer-1 input features (2 per thread)
    #pragma unroll
    for (int r = 0; r < 2; ++r) {
        const int f = tid + r * 256;
        const float xv = s[b * C + f];
        float* dst = &feat[f * 9];
        dst[0] = silu_f(xv);
        compute_bases(xv, g1, dst + 1);
    }
    __syncthreads();

    // Phase B: one wave per output
    const int o = obase + wave;
    const float* bw = bw1 + o * C;
    const float* sw = sw1 + (size_t)o * C * NBASES;
    const float* sc = sc1 + o * C;
    float acc = 0.0f;
    #pragma unroll
    for (int ii = 0; ii < C / 64; ++ii) {
        const int i = ii * 64 + lane;
        const float* f = &feat[i * 9];
        float t = 0.0f;
        #pragma unroll
        for (int k = 0; k < NBASES; ++k) t += f[1 + k] * sw[i * NBASES + k];
        acc += f[0] * bw[i] + t * sc[i];
    }
    acc = wave_reduce(acc);
    if (lane == 0) s1x2[b * HIDDEN + o] = silu_f(acc);   // fused inter-layer silu
}

// Kernel 3: KAN layer 2 + sigmoid. One WAVE per output (lane == feature,
// HIDDEN == 64 == wave width). grid = B*C/4 = 4096 blocks. Bases recomputed
// per lane in registers — no LDS, no barrier.
__global__ __launch_bounds__(256) void kan2_kernel(
        const float* __restrict__ s1x2,     // [B, HIDDEN]
        const float* __restrict__ grid2,    // [HIDDEN, 12] (rows identical)
        const float* __restrict__ bw2,      // [C, HIDDEN]
        const float* __restrict__ sw2,      // [C, HIDDEN, 8]
        const float* __restrict__ sc2,      // [C, HIDDEN]
        float* __restrict__ gate)           // [B, C]
{
    const int wave = threadIdx.x >> 6, lane = threadIdx.x & 63;
    const int gw = blockIdx.x * 4 + wave;   // [0, B*C)
    const int b = gw >> 9, o = gw & 511;

    float g2[NKNOTS];
    #pragma unroll
    for (int j = 0; j < NKNOTS; ++j) g2[j] = grid2[j];

    const float x2 = s1x2[b * HIDDEN + lane];
    float bs[NBASES];
    compute_bases(x2, g2, bs);

    const int wi = o * HIDDEN + lane;
    float t = 0.0f;
    #pragma unroll
    for (int k = 0; k < NBASES; ++k) t += bs[k] * sw2[(size_t)wi * NBASES + k];
    float acc = silu_f(x2) * bw2[wi] + t * sc2[wi];

    acc = wave_reduce(acc);
    if (lane == 0) gate[b * C + o] = 1.0f / (1.0f + __expf(-acc));
}

// Kernel 4: out = x * gate[plane]. One block per plane, 4 float4/thread.
__global__ __launch_bounds__(256) void scale_kernel(const float4* __restrict__ x,
                                                    const float* __restrict__ gate,
                                                    float4* __restrict__ out) {
    const float g = gate[blockIdx.x];
    const float4* xp = x + (size_t)blockIdx.x * (HW / 4);
    float4* op = out + (size_t)blockIdx.x * (HW / 4);
    #pragma unroll
    for (int j = 0; j < 4; ++j) {
        float4 v = xp[threadIdx.x + j * 256];
        v.x *= g; v.y *= g; v.z *= g; v.w *= g;
        op[threadIdx.x + j * 256] = v;
    }
}

extern "C" void kernel_launch(void* const* d_in, const int* in_sizes, int n_in,
                              void* d_out, int out_size, void* d_ws, size_t ws_size,
                              hipStream_t stream) {
    const float* x     = (const float*)d_in[0];
    const float* grid1 = (const float*)d_in[1];
    const float* bw1   = (const float*)d_in[2];
    const float* sw1   = (const float*)d_in[3];
    const float* sc1   = (const float*)d_in[4];
    const float* grid2 = (const float*)d_in[5];
    const float* bw2   = (const float*)d_in[6];
    const float* sw2   = (const float*)d_in[7];
    const float* sc2   = (const float*)d_in[8];
    float* out  = (float*)d_out;

    float* s    = (float*)d_ws;          // B*C      = 16384 floats
    float* s1x2 = s + B * C;             // B*HIDDEN =  2048 floats
    float* gate = s1x2 + B * HIDDEN;     // B*C      = 16384 floats

    mean_kernel<<<B * C / 4, 256, 0, stream>>>(x, s);
    kan1_kernel<<<B * (HIDDEN / 4), 256, 0, stream>>>(s, grid1, bw1, sw1, sc1, s1x2);
    kan2_kernel<<<B * C / 4, 256, 0, stream>>>(s1x2, grid2, bw2, sw2, sc2, gate);
    scale_kernel<<<B * C, 256, 0, stream>>>((const float4*)x, gate, (float4*)out);
}